// Round 7
// baseline (28.166 us; speedup 1.0000x reference)
//
#include <hip/hip_runtime.h>

// NSLayer: out = X + (-a*(X X^T) + b*(X X^T)^2) X per (b,c) slice, X: [512][64].
// Factored: G = X^T X (64x64), H = -a*G + b*G^2 (symmetric), out = X + X*H.
// bf16 MFMA (32x32x16), fp32 accumulate.
// Round 7: 2 slices per block (256 blocks x 512 threads, 1 block/CU).
// Cross-slice pipeline: slice-B HBM loads issued during slice-A pass-1 so
// B's read stream drains under A's compute bubble + store stream; A's stores
// drain under B's compute. Math/layout identical to round 5/6 (absmax 8192).

typedef __bf16 bf16;
typedef __attribute__((ext_vector_type(8)))  __bf16 bf16x8;
typedef __attribute__((ext_vector_type(4)))  __bf16 bf16x4;
typedef __attribute__((ext_vector_type(16))) float  f32x16;

namespace {

__device__ __forceinline__ int sxz(int d) { return ((d >> 1) ^ (d >> 4)) & 7; }

__device__ __forceinline__ bf16x4 cvt4(const float4 v) {
    bf16x4 r;
    r[0] = (bf16)v.x; r[1] = (bf16)v.y; r[2] = (bf16)v.z; r[3] = (bf16)v.w;
    return r;
}

// stage one 64-row chunk, transposed, 16B-granule swizzled
__device__ __forceinline__ void stage_chunk(bf16* XtMine, const bf16x4 (&x)[4],
                                            int s_nq, int s_dq) {
#pragma unroll
    for (int r = 0; r < 4; ++r) {
        const int d = 4 * s_dq + r;
        bf16x4 v;
        v[0] = x[0][r]; v[1] = x[1][r]; v[2] = x[2][r]; v[3] = x[3][r];
        const int g = ((s_nq >> 1) ^ sxz(d)) & 7;
        *(bf16x4*)&XtMine[d * 72 + g * 8 + 4 * (s_nq & 1)] = v;
    }
}

__device__ __forceinline__ void mfma4(const bf16* XtMine, f32x16& acc,
                                      int rowA, int rowB, int sA, int sB, int l5) {
#pragma unroll
    for (int ks = 0; ks < 4; ++ks) {
        const int gw = 2 * ks + l5;
        bf16x8 a = *(const bf16x8*)&XtMine[rowA * 72 + ((gw ^ sA) & 7) * 8];
        bf16x8 b = *(const bf16x8*)&XtMine[rowB * 72 + ((gw ^ sB) & 7) * 8];
        acc = __builtin_amdgcn_mfma_f32_32x32x16_bf16(a, b, acc, 0, 0, 0);
    }
}

// G-reduce (sequential across halves) + early-stage Xr tile 0 + pass-2 (H)
__device__ __forceinline__ void make_H(const f32x16& acc, float av, float bv,
                                       bf16* Xr, const bf16x4 (&xr0)[4],
                                       float* Gp, bf16* Gbf, bf16* Hbf,
                                       int half, int w, int l31, int l5,
                                       int i32, int j32, int s_nq, int s_dq) {
    if (half == 0) {
#pragma unroll
        for (int q = 0; q < 16; ++q) {
            const int r = (q & 3) + 8 * (q >> 2) + 4 * l5;   // C/D row (m74/m101)
            Gp[(i32 + r) * 68 + j32 + l31] = acc[q];
        }
    }
    // Xt dead after pass-1's trailing barrier: stage pass-3 tile 0 now
#pragma unroll
    for (int rn = 0; rn < 4; ++rn)
        *(bf16x4*)&Xr[(64 * half + 4 * s_nq + rn) * 72 + 4 * s_dq] = xr0[rn];
    __syncthreads();
    if (half == 1) {
#pragma unroll
        for (int q = 0; q < 16; ++q) {
            const int r  = (q & 3) + 8 * (q >> 2) + 4 * l5;
            const int ii = i32 + r;
            const int jj = j32 + l31;
            Gbf[ii * 72 + jj] = (bf16)(acc[q] + Gp[ii * 68 + jj]);
        }
    }
    __syncthreads();
    if (w < 4) {
        const int pi = (w >> 1) * 32;
        const int pj = (w & 1) * 32;
        f32x16 h;
#pragma unroll
        for (int q = 0; q < 16; ++q) h[q] = 0.f;
#pragma unroll
        for (int ks = 0; ks < 4; ++ks) {
            // G symmetric: both operands are row reads of Gbf
            bf16x8 a = *(const bf16x8*)&Gbf[(pi + l31) * 72 + ks * 16 + 8 * l5];
            bf16x8 b = *(const bf16x8*)&Gbf[(pj + l31) * 72 + ks * 16 + 8 * l5];
            h = __builtin_amdgcn_mfma_f32_32x32x16_bf16(a, b, h, 0, 0, 0);
        }
#pragma unroll
        for (int q = 0; q < 16; ++q) {
            const int r  = (q & 3) + 8 * (q >> 2) + 4 * l5;
            const int ii = pi + r;
            const int jj = pj + l31;
            Hbf[ii * 72 + jj] = (bf16)(bv * h[q] - av * (float)Gbf[ii * 72 + jj]);
        }
    }
    __syncthreads();
}

// out = X + X*H over 4 128-row tiles; tile 0 pre-staged in Xr
__device__ __forceinline__ void pass3(bf16* Xr, const bf16x4 (&xr)[4][4],
                                      const bf16* Hbf, float* O,
                                      int half, int l31, int l5, int nb, int db,
                                      int s_nq, int s_dq) {
#pragma unroll
    for (int it = 0; it < 4; ++it) {
        f32x16 o;
#pragma unroll
        for (int q = 0; q < 16; ++q) o[q] = 0.f;
#pragma unroll
        for (int ks = 0; ks < 4; ++ks) {
            bf16x8 a = *(const bf16x8*)&Xr [(nb + l31) * 72 + ks * 16 + 8 * l5];
            bf16x8 b = *(const bf16x8*)&Hbf[(db + l31) * 72 + ks * 16 + 8 * l5];
            o = __builtin_amdgcn_mfma_f32_32x32x16_bf16(a, b, o, 0, 0, 0);
        }
#pragma unroll
        for (int q = 0; q < 16; ++q) {
            const int rl = (q & 3) + 8 * (q >> 2) + 4 * l5;
            const int nl = nb + rl;
            const int d  = db + l31;
            O[(size_t)(it * 128 + nl) * 64 + d] = o[q] + (float)Xr[nl * 72 + d];
        }
        if (it < 3) {
            __syncthreads();   // all Xr reads of tile it done
#pragma unroll
            for (int rn = 0; rn < 4; ++rn)
                *(bf16x4*)&Xr[(64 * half + 4 * s_nq + rn) * 72 + 4 * s_dq] = xr[it + 1][rn];
            __syncthreads();   // tile it+1 staged
        }
    }
}

__global__ __launch_bounds__(512, 2)
void ns_pair(const float* __restrict__ inp, const float* __restrict__ aw,
             const float* __restrict__ bw, float* __restrict__ out) {
    // LDS map (72704 B, 1 block/CU):
    //   [0,18432):      slice A: Xt0/Xt1 (pass-1) then Xr[128][72] (pass-3)
    //   [18432,36864):  slice B: Xt0/Xt1 then Xr
    //   [36864,54272):  Gp[64][68]f32 (reused A then B)
    //   [54272,63488):  Gbf[64][72]bf16
    //   [63488,72704):  Hbf[64][72]bf16
    __shared__ unsigned char smem[72704] __attribute__((aligned(128)));
    bf16*  const SA  = (bf16*)smem;
    bf16*  const SB  = (bf16*)(smem + 18432);
    float* const Gp  = (float*)(smem + 36864);
    bf16*  const Gbf = (bf16*)(smem + 54272);
    bf16*  const Hbf = (bf16*)(smem + 63488);

    const int blk    = blockIdx.x;
    const int sliceA = 2 * blk;
    const int sliceB = 2 * blk + 1;
    const float* __restrict__ XA = inp + (size_t)sliceA * 32768;
    const float* __restrict__ XB = inp + (size_t)sliceB * 32768;
    float* __restrict__ OA       = out + (size_t)sliceA * 32768;
    float* __restrict__ OB       = out + (size_t)sliceB * 32768;

    const int t    = threadIdx.x;
    const int lane = t & 63;
    const int w    = t >> 6;
    const int l31  = lane & 31;
    const int l5   = lane >> 5;
    const int half = t >> 8;       // == w>>2
    const int th   = t & 255;
    const int s_nq = th >> 4;
    const int s_dq = th & 15;

    // thread in half h owns chunks (2s+h): rows 64*h + 128*s + 4*s_nq + rn
    const float* __restrict__ XbA = XA + (size_t)(64 * half + 4 * s_nq) * 64 + 4 * s_dq;
    const float* __restrict__ XbB = XB + (size_t)(64 * half + 4 * s_nq) * 64 + 4 * s_dq;

    // issue slice-A chunk-0 loads immediately
    float4 rv[2][4];
#pragma unroll
    for (int rn = 0; rn < 4; ++rn)
        rv[0][rn] = *(const float4*)&XbA[(size_t)rn * 64];

    const float avA = aw[sliceA & 63], bvA = bw[sliceA & 63];
    const float avB = aw[sliceB & 63], bvB = bw[sliceB & 63];

    const int tile = w & 3;
    const int i32  = (tile >> 1) * 32;
    const int j32  = (tile & 1) * 32;
    const int rowA = i32 + l31;
    const int rowB = j32 + l31;
    const int sA   = sxz(rowA);
    const int sB   = sxz(rowB);
    const int nb   = (w >> 1) * 32;   // pass-3 n-block
    const int db   = (w & 1) * 32;    // pass-3 d-block

    bf16* const XtA = SA + half * 4608;   // 9216 B per half-buffer
    bf16* const XtB = SB + half * 4608;

    // ================= slice A: pass 1 (stream from HBM, prefetch-1) ========
    f32x16 acc;
#pragma unroll
    for (int q = 0; q < 16; ++q) acc[q] = 0.f;

    bf16x4 xrA[4][4];
    float4 rvB[4][4];

#pragma unroll
    for (int it = 0; it < 4; ++it) {
        if (it < 3) {
#pragma unroll
            for (int rn = 0; rn < 4; ++rn)
                rv[(it + 1) & 1][rn] =
                    *(const float4*)&XbA[(size_t)(128 * (it + 1) + rn) * 64];
        }
        if (it == 2) {
            // issue ALL slice-B loads: they drain under A's bubble + stores
#pragma unroll
            for (int s = 0; s < 4; ++s)
#pragma unroll
                for (int rn = 0; rn < 4; ++rn)
                    rvB[s][rn] = *(const float4*)&XbB[(size_t)(128 * s + rn) * 64];
        }
#pragma unroll
        for (int rn = 0; rn < 4; ++rn) xrA[it][rn] = cvt4(rv[it & 1][rn]);
        stage_chunk(XtA, xrA[it], s_nq, s_dq);
        __syncthreads();
        mfma4(XtA, acc, rowA, rowB, sA, sB, l5);
        __syncthreads();
    }

    make_H(acc, avA, bvA, SA, xrA[0], Gp, Gbf, Hbf,
           half, w, l31, l5, i32, j32, s_nq, s_dq);
    pass3(SA, xrA, Hbf, OA, half, l31, l5, nb, db, s_nq, s_dq);

    // ================= slice B: data already in regs ========================
    bf16x4 xrB[4][4];
#pragma unroll
    for (int s = 0; s < 4; ++s)
#pragma unroll
        for (int rn = 0; rn < 4; ++rn) xrB[s][rn] = cvt4(rvB[s][rn]);

    f32x16 accB;
#pragma unroll
    for (int q = 0; q < 16; ++q) accB[q] = 0.f;

#pragma unroll
    for (int it = 0; it < 4; ++it) {
        stage_chunk(XtB, xrB[it], s_nq, s_dq);
        __syncthreads();
        mfma4(XtB, accB, rowA, rowB, sA, sB, l5);
        __syncthreads();
    }

    make_H(accB, avB, bvB, SB, xrB[0], Gp, Gbf, Hbf,
           half, w, l31, l5, i32, j32, s_nq, s_dq);
    pass3(SB, xrB, Hbf, OB, half, l31, l5, nb, db, s_nq, s_dq);
}

}  // namespace

extern "C" void kernel_launch(void* const* d_in, const int* in_sizes, int n_in,
                              void* d_out, int out_size, void* d_ws, size_t ws_size,
                              hipStream_t stream) {
    const float* inp = (const float*)d_in[0];
    const float* aw  = (const float*)d_in[1];
    const float* bw  = (const float*)d_in[2];
    float* out       = (float*)d_out;

    // 512 slices, 2 per block: 256 blocks x 512 threads (1 block/CU).
    ns_pair<<<dim3(256), dim3(512), 0, stream>>>(inp, aw, bw, out);
}

// Round 8
// 25.411 us; speedup vs baseline: 1.1084x; 1.1084x over previous
//
#include <hip/hip_runtime.h>

// NSLayer: out = X + (-a*(X X^T) + b*(X X^T)^2) X per (b,c) slice, X: [512][64].
// Factored: G = X^T X (64x64), H = -a*G + b*G^2 (symmetric), out = X + X*H.
// bf16 MFMA (32x32x16), fp32 accumulate. 512 blocks x 512 threads, 2 blocks/CU.
// Round 8 (base = round 5, best at 25.5us), barrier/bubble reduction only:
//   * pass-1 Xt double-buffered: 1 barrier/chunk (8 -> 5 barriers)
//   * chunk ownership flipped (half h owns chunks 4*(1-h)+s): half-1 owns
//     pass-3 tiles 0,1 and pre-stages BOTH into Xr during the G/H bubble
//   * pass-3 ping-pong over 2 Xr buffers: stage tile t+1 during tile t's
//     MFMA (6 -> 3 barriers); stores flow nearly back-to-back
// Math/layout identical to round 5 (absmax 8192 expected).

typedef __bf16 bf16;
typedef __attribute__((ext_vector_type(8)))  __bf16 bf16x8;
typedef __attribute__((ext_vector_type(4)))  __bf16 bf16x4;
typedef __attribute__((ext_vector_type(16))) float  f32x16;

namespace {

__device__ __forceinline__ int sxz(int d) { return ((d >> 1) ^ (d >> 4)) & 7; }

__global__ __launch_bounds__(512, 2)
void ns_mfma(const float* __restrict__ inp, const float* __restrict__ aw,
             const float* __restrict__ bw, float* __restrict__ out) {
    // LDS map (72704 B, 2 blocks/CU):
    //   [0,36864):      pass1: Xt[half][buf] = 4 x 9216 ([64][72]bf16 each)
    //                   pass3: Xr0[128][72]bf16 (=[0,18432)) + Xr1 (=[18432,36864))
    //   [36864,54272):  Gp[64][68]f32 partial
    //   [54272,63488):  Gbf[64][72]bf16
    //   [63488,72704):  Hbf[64][72]bf16
    __shared__ unsigned char smem[72704] __attribute__((aligned(128)));
    float* const Gp  = (float*)(smem + 36864);
    bf16*  const Gbf = (bf16*)(smem + 54272);
    bf16*  const Hbf = (bf16*)(smem + 63488);
    bf16*  const Xr0 = (bf16*)smem;
    bf16*  const Xr1 = (bf16*)(smem + 18432);

    const int slice = blockIdx.x;                // b*64 + c
    const float* __restrict__ X = inp + (size_t)slice * 32768;
    float* __restrict__ O       = out + (size_t)slice * 32768;

    const int t    = threadIdx.x;
    const int lane = t & 63;
    const int w    = t >> 6;       // wave 0..7
    const int l31  = lane & 31;
    const int l5   = lane >> 5;    // 0/1
    const int half = t >> 8;       // == w>>2
    const int th   = t & 255;
    const int s_nq = th >> 4;      // 0..15
    const int s_dq = th & 15;      // 0..15

    // half h owns chunks 4*(1-h)+s, s=0..3 (rows 256*(1-h)+64*s+4*s_nq+rn).
    // => half 1 owns chunks 0..3 = pass-3 tiles 0,1 (pre-staged in G bubble);
    //    half 0 owns chunks 4..7 = tiles 2,3 (staged during pass-3 pipeline).
    const float* __restrict__ Xbase =
        X + (size_t)(256 * (1 - half) + 4 * s_nq) * 64 + 4 * s_dq;

    // ====== Load entire X share into regs (once), convert to bf16 ==========
    bf16x4 xr[4][4];
    {
        float4 rv[4][4];
#pragma unroll
        for (int s = 0; s < 4; ++s)
#pragma unroll
            for (int rn = 0; rn < 4; ++rn)
                rv[s][rn] = *(const float4*)&Xbase[(size_t)(64 * s + rn) * 64];
#pragma unroll
        for (int s = 0; s < 4; ++s)
#pragma unroll
            for (int rn = 0; rn < 4; ++rn) {
                xr[s][rn][0] = (bf16)rv[s][rn].x;
                xr[s][rn][1] = (bf16)rv[s][rn].y;
                xr[s][rn][2] = (bf16)rv[s][rn].z;
                xr[s][rn][3] = (bf16)rv[s][rn].w;
            }
    }
    const float av = aw[slice & 63];
    const float bv = bw[slice & 63];

    // ================= Pass 1: G = X^T X, K-split across halves ============
    f32x16 acc;
#pragma unroll
    for (int q = 0; q < 16; ++q) acc[q] = 0.f;

    const int tile = w & 3;
    const int i32  = (tile >> 1) * 32;
    const int j32  = (tile & 1) * 32;
    const int rowA = i32 + l31;
    const int rowB = j32 + l31;
    const int sA   = sxz(rowA);
    const int sB   = sxz(rowB);

    unsigned char* const XtH = smem + half * 18432;   // this half's 2 buffers

#pragma unroll
    for (int it = 0; it < 4; ++it) {
        bf16* const Xt = (bf16*)(XtH + (it & 1) * 9216);
        // stage chunk (4*(1-half)+it) transposed, 16B-granule swizzled
#pragma unroll
        for (int r = 0; r < 4; ++r) {
            const int d = 4 * s_dq + r;
            bf16x4 v;
            v[0] = xr[it][0][r]; v[1] = xr[it][1][r];
            v[2] = xr[it][2][r]; v[3] = xr[it][3][r];
            const int g = ((s_nq >> 1) ^ sxz(d)) & 7;
            *(bf16x4*)&Xt[d * 72 + g * 8 + 4 * (s_nq & 1)] = v;
        }
        __syncthreads();   // single barrier/chunk (double-buffered Xt)
#pragma unroll
        for (int ks = 0; ks < 4; ++ks) {
            const int gw = 2 * ks + l5;
            bf16x8 a = *(const bf16x8*)&Xt[rowA * 72 + ((gw ^ sA) & 7) * 8];
            bf16x8 b = *(const bf16x8*)&Xt[rowB * 72 + ((gw ^ sB) & 7) * 8];
            acc = __builtin_amdgcn_mfma_f32_32x32x16_bf16(a, b, acc, 0, 0, 0);
        }
    }
    __syncthreads();   // B0: all pass-1 LDS reads done; Xt space now dead

    // ====== G bubble: half0 -> Gp; half1 pre-stages pass-3 tiles 0,1 =======
    if (half == 0) {
#pragma unroll
        for (int q = 0; q < 16; ++q) {
            const int r = (q & 3) + 8 * (q >> 2) + 4 * l5;   // C/D row (m74/m101)
            Gp[(i32 + r) * 68 + j32 + l31] = acc[q];
        }
    } else {
        // half1's xr[s] = chunk s = tile (s>>1), rows 64*(s&1)..+63
#pragma unroll
        for (int s = 0; s < 4; ++s) {
            bf16* const Xr = (s >> 1) ? Xr1 : Xr0;
            const int rowbase = 64 * (s & 1) + 4 * s_nq;
#pragma unroll
            for (int rn = 0; rn < 4; ++rn)
                *(bf16x4*)&Xr[(rowbase + rn) * 72 + 4 * s_dq] = xr[s][rn];
        }
    }
    __syncthreads();   // B1
    if (half == 1) {
#pragma unroll
        for (int q = 0; q < 16; ++q) {
            const int r  = (q & 3) + 8 * (q >> 2) + 4 * l5;
            const int ii = i32 + r;
            const int jj = j32 + l31;
            Gbf[ii * 72 + jj] = (bf16)(acc[q] + Gp[ii * 68 + jj]);
        }
    }
    __syncthreads();   // B2

    // ================= Pass 2: H = b*G^2 - a*G (waves 0-3) =================
    if (w < 4) {
        const int pi = (w >> 1) * 32;
        const int pj = (w & 1) * 32;
        f32x16 h;
#pragma unroll
        for (int q = 0; q < 16; ++q) h[q] = 0.f;
#pragma unroll
        for (int ks = 0; ks < 4; ++ks) {
            // G symmetric: both operands are row reads of Gbf
            bf16x8 a = *(const bf16x8*)&Gbf[(pi + l31) * 72 + ks * 16 + 8 * l5];
            bf16x8 b = *(const bf16x8*)&Gbf[(pj + l31) * 72 + ks * 16 + 8 * l5];
            h = __builtin_amdgcn_mfma_f32_32x32x16_bf16(a, b, h, 0, 0, 0);
        }
#pragma unroll
        for (int q = 0; q < 16; ++q) {
            const int r  = (q & 3) + 8 * (q >> 2) + 4 * l5;
            const int ii = pi + r;
            const int jj = pj + l31;
            Hbf[ii * 72 + jj] = (bf16)(bv * h[q] - av * (float)Gbf[ii * 72 + jj]);
        }
    }
    __syncthreads();   // B3: Hbf ready; tiles 0,1 already staged

    // ================= Pass 3: out = X + X*H, ping-pong Xr =================
    const int nb = (w >> 1) * 32;   // n-block within 128-row tile
    const int db = (w & 1) * 32;    // d-block

#pragma unroll
    for (int tt = 0; tt < 4; ++tt) {
        if (tt > 0) __syncthreads();   // B4/B5/B6
        if (half == 0 && (tt == 1 || tt == 2)) {
            // stage tile tt+1 into buf (tt+1)&1; half0's xr[s] = chunk 4+s
            bf16* const Xr = ((tt + 1) & 1) ? Xr1 : Xr0;
#pragma unroll
            for (int ss = 0; ss < 2; ++ss) {
                const int s       = 2 * (tt - 1) + ss;
                const int rowbase = 64 * ss + 4 * s_nq;
#pragma unroll
                for (int rn = 0; rn < 4; ++rn)
                    *(bf16x4*)&Xr[(rowbase + rn) * 72 + 4 * s_dq] = xr[s][rn];
            }
        }
        const bf16* const Xr = (tt & 1) ? Xr1 : Xr0;

        f32x16 o;
#pragma unroll
        for (int q = 0; q < 16; ++q) o[q] = 0.f;
#pragma unroll
        for (int ks = 0; ks < 4; ++ks) {
            bf16x8 a = *(const bf16x8*)&Xr [(nb + l31) * 72 + ks * 16 + 8 * l5];
            bf16x8 b = *(const bf16x8*)&Hbf[(db + l31) * 72 + ks * 16 + 8 * l5];
            o = __builtin_amdgcn_mfma_f32_32x32x16_bf16(a, b, o, 0, 0, 0);
        }
        // epilogue: out = X + X*H; 128B-contiguous dword stores
#pragma unroll
        for (int q = 0; q < 16; ++q) {
            const int rl = (q & 3) + 8 * (q >> 2) + 4 * l5;
            const int nl = nb + rl;
            const int d  = db + l31;
            O[(size_t)(tt * 128 + nl) * 64 + d] = o[q] + (float)Xr[nl * 72 + d];
        }
    }
}

}  // namespace

extern "C" void kernel_launch(void* const* d_in, const int* in_sizes, int n_in,
                              void* d_out, int out_size, void* d_ws, size_t ws_size,
                              hipStream_t stream) {
    const float* inp = (const float*)d_in[0];
    const float* aw  = (const float*)d_in[1];
    const float* bw  = (const float*)d_in[2];
    float* out       = (float*)d_out;

    ns_mfma<<<dim3(512), dim3(512), 0, stream>>>(inp, aw, bw, out);
}